// Round 7
// baseline (201.765 us; speedup 1.0000x reference)
//
#include <hip/hip_runtime.h>
#include <hip/hip_bf16.h>

typedef __attribute__((ext_vector_type(8))) short short8;
typedef __attribute__((ext_vector_type(4))) float f32x4;
typedef __attribute__((ext_vector_type(16))) float f32x16;
typedef __attribute__((ext_vector_type(4))) unsigned short u16x4;
typedef __attribute__((ext_vector_type(8))) unsigned short u16x8;
typedef __attribute__((ext_vector_type(4))) unsigned int u32x4;

__device__ __forceinline__ unsigned short f2b(float f) {
  __hip_bfloat16 h = __float2bfloat16(f);
  return __builtin_bit_cast(unsigned short, h);
}

__device__ __forceinline__ void gload_lds16(const void* g, void* l) {
  __builtin_amdgcn_global_load_lds(
      (const __attribute__((address_space(1))) unsigned int*)g,
      (__attribute__((address_space(3))) unsigned int*)l, 16, 0, 0);
}

__device__ __forceinline__ f32x16 mfma32(short8 a, short8 b, f32x16 c) {
  return __builtin_amdgcn_mfma_f32_32x32x16_bf16(a, b, c, 0, 0, 0);
}

__device__ __forceinline__ unsigned int cvtpk(float a, float b) {
  unsigned int r;
  asm("v_cvt_pk_bf16_f32 %0, %1, %2" : "=v"(r) : "v"(a), "v"(b));
  return r;
}

// ---------------- prepass: f32 -> bf16 linear convert ----------------
__global__ __launch_bounds__(256) void cvt_f32_bf16(const float* __restrict__ s,
                                                    unsigned short* __restrict__ d,
                                                    int n8) {
  int i = blockIdx.x * 256 + threadIdx.x;
  if (i >= n8) return;
  const f32x4* sp = (const f32x4*)s;
  f32x4 a = sp[2 * i];
  f32x4 b = sp[2 * i + 1];
  u16x8 o;
  o[0] = f2b(a[0]); o[1] = f2b(a[1]); o[2] = f2b(a[2]); o[3] = f2b(a[3]);
  o[4] = f2b(b[0]); o[5] = f2b(b[1]); o[6] = f2b(b[2]); o[7] = f2b(b[3]);
  ((u16x8*)d)[i] = o;
}

// ------------- prepass: weight transpose+convert: Wt[n][k] = bf16(W[k][n]) ----
struct WtransParams {
  const float* w[6];
  unsigned short* wt[6];
};

__global__ __launch_bounds__(256) void wtrans(WtransParams p) {
  __shared__ float t[32][33];
  const int z = blockIdx.z;
  const float* W = p.w[z];
  unsigned short* Wt = p.wt[z];
  const int bx = blockIdx.x;
  const int by = blockIdx.y;
  const int tx = threadIdx.x, ty = threadIdx.y;
#pragma unroll
  for (int i = 0; i < 4; ++i)
    t[ty + 8 * i][tx] = W[(by * 32 + ty + 8 * i) * 1024 + bx * 32 + tx];
  __syncthreads();
#pragma unroll
  for (int i = 0; i < 4; ++i)
    Wt[(bx * 32 + ty + 8 * i) * 1024 + by * 32 + tx] = f2b(t[tx][ty + 8 * i]);
}

// ---------------- merged batched projection GEMM ----------------
struct GemmJob {
  const unsigned short* Wt;  // [1024][1024] bf16, n-major
  const float* bias;
  unsigned short* out;
  int S;
  int s_off;
  int sshift;  // log2 rows-per-batch
  int trans;   // 0: out[bh][s][64]; 1: out[bh][64][2304] (V transposed)
  float scale;
};
struct Gemm2Params {
  const unsigned short* Aw;
  const unsigned short* Ae;
  GemmJob job[8];
};

__global__ __launch_bounds__(256) void gemm_qkv(Gemm2Params p) {
  __shared__ unsigned short As[128 * 64];
  __shared__ unsigned short Bs[128 * 64];
  const int tid = threadIdx.x;
  const int w = tid >> 6, lane = tid & 63;
  const int c = lane & 15, g = lane >> 4;
  const int z = blockIdx.z;
  const int y = blockIdx.y;
  const bool isw = y < 32;
  const GemmJob j = p.job[isw ? z : z + 4];
  const unsigned short* A = isw ? p.Aw : p.Ae;
  const long arow0 = (long)(isw ? y : y - 32) * 128;
  const unsigned short* B = j.Wt;
  const long brow0 = (long)blockIdx.x * 128;

  f32x4 acc[4][4] = {};

  for (int kt = 0; kt < 16; ++kt) {
    __syncthreads();
#pragma unroll
    for (int i = 0; i < 4; ++i) {
      int ch = i * 256 + tid;
      int row = ch >> 3;
      int k8 = ((ch & 7) ^ (row & 7)) << 3;
      const unsigned short* ga = A + (arow0 + row) * 1024 + kt * 64 + k8;
      const unsigned short* gb = B + (brow0 + row) * 1024 + kt * 64 + k8;
      gload_lds16(ga, As + (i * 256 + w * 64) * 8);
      gload_lds16(gb, Bs + (i * 256 + w * 64) * 8);
    }
    __syncthreads();
#pragma unroll
    for (int kf = 0; kf < 2; ++kf) {
      short8 av[4], bv[4];
#pragma unroll
      for (int mf = 0; mf < 4; ++mf) {
        int row = (w >> 1) * 64 + mf * 16 + c;
        int byte = (row * 128 + (kf * 32 + g * 8) * 2) ^ ((row & 7) << 4);
        av[mf] = *(const short8*)((const char*)As + byte);
      }
#pragma unroll
      for (int nf = 0; nf < 4; ++nf) {
        int row = (w & 1) * 64 + nf * 16 + c;
        int byte = (row * 128 + (kf * 32 + g * 8) * 2) ^ ((row & 7) << 4);
        bv[nf] = *(const short8*)((const char*)Bs + byte);
      }
      __builtin_amdgcn_s_setprio(1);
#pragma unroll
      for (int mf = 0; mf < 4; ++mf)
#pragma unroll
        for (int nf = 0; nf < 4; ++nf)
          acc[mf][nf] = __builtin_amdgcn_mfma_f32_16x16x32_bf16(av[mf], bv[nf],
                                                                acc[mf][nf], 0, 0, 0);
      __builtin_amdgcn_s_setprio(0);
    }
  }

  float biasv[4];
#pragma unroll
  for (int nf = 0; nf < 4; ++nf) {
    int n = (int)brow0 + (w & 1) * 64 + nf * 16 + c;
    biasv[nf] = j.bias[n];
  }
  const int smask = (1 << j.sshift) - 1;
  if (j.trans) {
#pragma unroll
    for (int mf = 0; mf < 4; ++mf) {
      int m0 = (int)arow0 + (w >> 1) * 64 + mf * 16 + g * 4;
      int b_ = m0 >> j.sshift;
      int s = (m0 & smask) + j.s_off;
#pragma unroll
      for (int nf = 0; nf < 4; ++nf) {
        int n = (int)brow0 + (w & 1) * 64 + nf * 16 + c;
        int hh = n >> 6, dd = n & 63;
        u16x4 pv;
#pragma unroll
        for (int r = 0; r < 4; ++r)
          pv[r] = f2b((acc[mf][nf][r] + biasv[nf]) * j.scale);
        *(u16x4*)(j.out + (((long)b_ * 16 + hh) * 64 + dd) * 2304 + s) = pv;
      }
    }
  } else {
#pragma unroll
    for (int mf = 0; mf < 4; ++mf) {
#pragma unroll
      for (int r = 0; r < 4; ++r) {
        int m = (int)arow0 + (w >> 1) * 64 + mf * 16 + g * 4 + r;
        int b_ = m >> j.sshift;
        int s = (m & smask) + j.s_off;
#pragma unroll
        for (int nf = 0; nf < 4; ++nf) {
          int n = (int)brow0 + (w & 1) * 64 + nf * 16 + c;
          int hh = n >> 6, dd = n & 63;
          float v = (acc[mf][nf][r] + biasv[nf]) * j.scale;
          j.out[(((long)b_ * 16 + hh) * j.S + s) * 64 + dd] = f2b(v);
        }
      }
    }
  }
}

// ---------------- flash attention (key-split x2, V direct-to-register) -------
// 1152 blocks (XCD-grouped), 4 waves x 32 q-rows, 64-key tiles, K dbuf in LDS
// (16 KiB), V fragments loaded global->reg (L2-resident), issued early (T14).
// P = exp2(st) unnormalized; the common scale cancels in the merge divide.
__global__ __launch_bounds__(256) void attn_kernel(
    const unsigned short* __restrict__ qw2w, const unsigned short* __restrict__ qw2e,
    const unsigned short* __restrict__ qe2w, const unsigned short* __restrict__ qe2e,
    const unsigned short* __restrict__ Kg, const unsigned short* __restrict__ Vtg,
    float* __restrict__ po0, float* __restrict__ po1, float* __restrict__ lbuf) {
  __shared__ unsigned short smem[8192];  // 16 KiB: K dbuf 2 x 8 KB

  const int tid = threadIdx.x;
  const int w = tid >> 6, lane = tid & 63;
  const int l31 = lane & 31, hf = lane >> 5;

  // XCD-grouped bijective remap: 1152 = 8 * 144; work = bh*36 + tile*2 + part
  const int flat = blockIdx.x;
  const int work = (flat & 7) * 144 + (flat >> 3);
  const int part = work & 1;
  const int tile = (work % 36) >> 1;
  const int hb = work / 36;
  const int head = hb & 15, b = hb >> 4;

  const bool isw = tile < 16;
  const int Sq = isw ? 2048 : 256;
  const int q0 = (isw ? tile : tile - 16) * 128 + w * 32;
  const int bh = b * 16 + head;
  const unsigned short* Qa =
      (isw ? qw2w : qe2w) + ((long)bh * Sq + q0 + l31) * 64 + hf * 8;
  const unsigned short* Qb =
      (isw ? qw2e : qe2e) + ((long)bh * Sq + q0 + l31) * 64 + hf * 8;
  const unsigned short* Kb = Kg + (long)bh * 2304 * 64;
  const unsigned short* Vtb = Vtg + (long)bh * 64 * 2304;

  short8 qcur[4];
#pragma unroll
  for (int kf = 0; kf < 4; ++kf) qcur[kf] = *(const short8*)(Qa + kf * 16);

  f32x16 o[2] = {};
  float lrun = 0.f;

  auto stage = [&](int t, int bufi) {
    const unsigned short* Kt = Kb + t * 4096;
    unsigned short* Klp = smem + bufi * 4096;
#pragma unroll
    for (int i = 0; i < 2; ++i) {
      int ch = i * 256 + tid;
      int row = ch >> 3, c8 = ch & 7;
      int col = (c8 ^ (row & 7)) << 3;
      gload_lds16(Kt + row * 64 + col, Klp + (i * 256 + (tid & 192)) * 8);
    }
  };

  const int t0 = part * 18, t1 = t0 + 18;
  stage(t0, 0);
  __syncthreads();
  int cur = 0;

  for (int t = t0; t < t1; ++t) {
    if (t == 32) {  // entity-key region: switch to the *2e query
#pragma unroll
      for (int kf = 0; kf < 4; ++kf) qcur[kf] = *(const short8*)(Qb + kf * 16);
    }
    if (t + 1 < t1) stage(t + 1, cur ^ 1);

    // V fragments: direct global->reg (L2-resident), issued early so QK+softmax
    // hides the latency. Lane (l31,hf) A-frag = Vt[mf*32+l31][t*64+ks*16+hf*8].
    short8 vfr[4][2];
#pragma unroll
    for (int ks = 0; ks < 4; ++ks)
#pragma unroll
      for (int mf = 0; mf < 2; ++mf)
        vfr[ks][mf] = *(const short8*)(Vtb + (mf * 32 + l31) * 2304 + t * 64 +
                                       ks * 16 + hf * 8);

    const char* Kbase = (const char*)(smem + cur * 4096);

    // QK^T: ST[key][q], 2 key-groups of 32
    f32x16 st[2] = {};
#pragma unroll
    for (int kg = 0; kg < 2; ++kg) {
      int row = kg * 32 + l31;
      int rb = (row * 128) | (hf * 16);
      int sw = (row & 7) << 4;
      short8 kfr[4];
#pragma unroll
      for (int kf = 0; kf < 4; ++kf)
        kfr[kf] = *(const short8*)(Kbase + ((rb + kf * 32) ^ sw));
      __builtin_amdgcn_s_setprio(1);
#pragma unroll
      for (int kf = 0; kf < 4; ++kf) st[kg] = mfma32(kfr[kf], qcur[kf], st[kg]);
      __builtin_amdgcn_s_setprio(0);
    }

    // softmax: P = exp2(st), no max subtraction (scale cancels in merge).
    // 4 independent accumulators break the serial sum chain.
    float s0 = 0.f, s1 = 0.f, s2 = 0.f, s3 = 0.f;
#pragma unroll
    for (int kg = 0; kg < 2; ++kg) {
#pragma unroll
      for (int r = 0; r < 16; r += 4) {
        float p0 = __builtin_amdgcn_exp2f(st[kg][r + 0]);
        float p1 = __builtin_amdgcn_exp2f(st[kg][r + 1]);
        float p2 = __builtin_amdgcn_exp2f(st[kg][r + 2]);
        float p3 = __builtin_amdgcn_exp2f(st[kg][r + 3]);
        st[kg][r + 0] = p0; st[kg][r + 1] = p1;
        st[kg][r + 2] = p2; st[kg][r + 3] = p3;
        s0 += p0; s1 += p1; s2 += p2; s3 += p3;
      }
    }
    lrun += (s0 + s1) + (s2 + s3);

    // P -> bf16 B-frags in-register (cvt_pk + permlane32_swap), PV accumulate
#pragma unroll
    for (int kg = 0; kg < 2; ++kg)
#pragma unroll
      for (int hs = 0; hs < 2; ++hs) {
        const int rbase = hs * 8;
        unsigned int a0 = cvtpk(st[kg][rbase + 0], st[kg][rbase + 1]);
        unsigned int a1 = cvtpk(st[kg][rbase + 2], st[kg][rbase + 3]);
        unsigned int b0 = cvtpk(st[kg][rbase + 4], st[kg][rbase + 5]);
        unsigned int b1 = cvtpk(st[kg][rbase + 6], st[kg][rbase + 7]);
        asm("v_permlane32_swap_b32 %0, %1" : "+v"(a0), "+v"(b0));
        asm("v_permlane32_swap_b32 %0, %1" : "+v"(a1), "+v"(b1));
        u32x4 pw;
        pw[0] = a0; pw[1] = a1; pw[2] = b0; pw[3] = b1;
        short8 pf = __builtin_bit_cast(short8, pw);
        const int ks = kg * 2 + hs;
        __builtin_amdgcn_s_setprio(1);
        o[0] = mfma32(vfr[ks][0], pf, o[0]);
        o[1] = mfma32(vfr[ks][1], pf, o[1]);
        __builtin_amdgcn_s_setprio(0);
      }

    __syncthreads();
    cur ^= 1;
  }

  // epilogue: combine lane halves, write UNNORMALIZED partial o + l
  float ltot = lrun + __shfl_xor(lrun, 32);

  const int sgb = (isw ? 0 : 2048) + q0;
  if (hf == 0) lbuf[(long)part * 73728 + bh * 2304 + sgb + l31] = ltot;

  float* po = part ? po1 : po0;
  float* ob = isw ? po + (((long)b * 2048 + q0) * 1024 + head * 64)
                  : po + (long)2 * 2048 * 1024 +
                        (((long)b * 256 + q0) * 1024 + head * 64);

  // per-wave private 4KB transpose buffer (LDS reused), two d-rounds of 32
  float* E = (float*)smem + w * 1024;
#pragma unroll
  for (int p = 0; p < 2; ++p) {
#pragma unroll
    for (int rg = 0; rg < 4; ++rg) {
      int off = rg * 8 + hf * 4;
      f32x4 v;
      v[0] = o[p][rg * 4 + 0];
      v[1] = o[p][rg * 4 + 1];
      v[2] = o[p][rg * 4 + 2];
      v[3] = o[p][rg * 4 + 3];
      *(f32x4*)(E + l31 * 32 + (off ^ ((l31 & 7) << 2))) = v;
    }
    asm volatile("s_waitcnt lgkmcnt(0)" ::: "memory");
    __builtin_amdgcn_sched_barrier(0);
#pragma unroll
    for (int i = 0; i < 4; ++i) {
      int qr = i * 8 + (lane >> 3);
      int cc = (lane & 7) * 4;
      f32x4 v = *(const f32x4*)(E + qr * 32 + (cc ^ ((qr & 7) << 2)));
      *(f32x4*)(ob + (long)qr * 1024 + p * 32 + cc) = v;
    }
    asm volatile("s_waitcnt lgkmcnt(0)" ::: "memory");
    __builtin_amdgcn_sched_barrier(0);
  }
}

// ---------------- merge: out = (o0 + o1) / (l0 + l1) ----------------
__global__ __launch_bounds__(256) void attn_merge(const float* __restrict__ po0,
                                                  const float* __restrict__ po1,
                                                  const float* __restrict__ lbuf,
                                                  float* __restrict__ out) {
  long i = ((long)blockIdx.x * 256 + threadIdx.x) * 4;
  if (i >= 4718592) return;
  int bh, sg;
  if (i < 4194304) {
    int b = (int)(i >> 21), s = (int)((i >> 10) & 2047), h = (int)((i >> 6) & 15);
    bh = b * 16 + h;
    sg = s;
  } else {
    long j = i - 4194304;
    int b = (int)(j >> 18), s = (int)((j >> 10) & 255), h = (int)((j >> 6) & 15);
    bh = b * 16 + h;
    sg = 2048 + s;
  }
  float l0 = lbuf[bh * 2304 + sg];
  float l1 = lbuf[73728 + bh * 2304 + sg];
  f32x4 a = *(const f32x4*)(po0 + i);
  f32x4 c = *(const f32x4*)(po1 + i);
  float inv = 1.f / (l0 + l1);
  f32x4 r = (a + c) * inv;
  *(f32x4*)(out + i) = r;
}

// ---------------- host ----------------
extern "C" void kernel_launch(void* const* d_in, const int* in_sizes, int n_in,
                              void* d_out, int out_size, void* d_ws, size_t ws_size,
                              hipStream_t stream) {
  (void)in_sizes; (void)n_in; (void)out_size; (void)ws_size;
  const float* word = (const float*)d_in[0];
  const float* ent = (const float*)d_in[1];

  char* ws = (char*)d_ws;
  size_t off = 0;
  auto alloc = [&](size_t bytes) {
    void* p = ws + off;
    off += (bytes + 255) & ~(size_t)255;
    return p;
  };
  // NOTE: po0 aliases [Xw, Xe, Wt) (22.0 MB front region) — those are dead by
  // the time attn_kernel writes po0 (all GEMMs complete first, same stream).
  unsigned short* Xw = (unsigned short*)alloc(4096ull * 1024 * 2);
  unsigned short* Xe = (unsigned short*)alloc(512ull * 1024 * 2);
  unsigned short* Wt[6];
  for (int i = 0; i < 6; ++i) Wt[i] = (unsigned short*)alloc(1024ull * 1024 * 2);
  unsigned short* qw2w = (unsigned short*)alloc(2ull * 16 * 2048 * 64 * 2);
  unsigned short* qw2e = (unsigned short*)alloc(2ull * 16 * 2048 * 64 * 2);
  unsigned short* qe2w = (unsigned short*)alloc(2ull * 16 * 256 * 64 * 2);
  unsigned short* qe2e = (unsigned short*)alloc(2ull * 16 * 256 * 64 * 2);
  unsigned short* Kbuf = (unsigned short*)alloc(2ull * 16 * 2304 * 64 * 2);
  unsigned short* Vtbuf = (unsigned short*)alloc(2ull * 16 * 64 * 2304 * 2);
  float* po1 = (float*)alloc(4718592ull * 4);
  float* lbuf = (float*)alloc(2ull * 73728 * 4);
  float* po0 = (float*)ws;  // aliases the dead prepass region

  cvt_f32_bf16<<<2048, 256, 0, stream>>>(word, Xw, 524288);
  cvt_f32_bf16<<<256, 256, 0, stream>>>(ent, Xe, 65536);

  WtransParams wp;
  wp.w[0] = (const float*)d_in[2];   // Wq
  wp.w[1] = (const float*)d_in[4];   // Wk
  wp.w[2] = (const float*)d_in[6];   // Wv
  wp.w[3] = (const float*)d_in[8];   // Ww2e
  wp.w[4] = (const float*)d_in[10];  // We2w
  wp.w[5] = (const float*)d_in[12];  // We2e
  for (int i = 0; i < 6; ++i) wp.wt[i] = Wt[i];
  wtrans<<<dim3(32, 32, 6), dim3(32, 8), 0, stream>>>(wp);

  const float* bq = (const float*)d_in[3];
  const float* bk = (const float*)d_in[5];
  const float* bv = (const float*)d_in[7];
  const float* bw2e = (const float*)d_in[9];
  const float* be2w = (const float*)d_in[11];
  const float* be2e = (const float*)d_in[13];
  const float qs = 0.125f * 1.44269504f;  // 1/sqrt(64) * log2(e): exp2-domain softmax

  Gemm2Params gp;
  gp.Aw = Xw;
  gp.Ae = Xe;
  gp.job[0] = {Wt[0], bq, qw2w, 2048, 0, 11, 0, qs};
  gp.job[1] = {Wt[3], bw2e, qw2e, 2048, 0, 11, 0, qs};
  gp.job[2] = {Wt[1], bk, Kbuf, 2304, 0, 11, 0, 1.f};
  gp.job[3] = {Wt[2], bv, Vtbuf, 2304, 0, 11, 1, 1.f};
  gp.job[4] = {Wt[4], be2w, qe2w, 256, 0, 8, 0, qs};
  gp.job[5] = {Wt[5], be2e, qe2e, 256, 0, 8, 0, qs};
  gp.job[6] = {Wt[1], bk, Kbuf, 2304, 2048, 8, 0, 1.f};
  gp.job[7] = {Wt[2], bv, Vtbuf, 2304, 2048, 8, 1, 1.f};
  gemm_qkv<<<dim3(8, 36, 4), 256, 0, stream>>>(gp);

  attn_kernel<<<1152, 256, 0, stream>>>(qw2w, qw2e, qe2w, qe2e, Kbuf, Vtbuf,
                                        po0, po1, lbuf);
  attn_merge<<<4608, 256, 0, stream>>>(po0, po1, lbuf, (float*)d_out);
}

// Round 8
// 154.899 us; speedup vs baseline: 1.3026x; 1.3026x over previous
//
#include <hip/hip_runtime.h>
#include <hip/hip_bf16.h>

typedef __attribute__((ext_vector_type(8))) short short8;
typedef __attribute__((ext_vector_type(4))) float f32x4;
typedef __attribute__((ext_vector_type(16))) float f32x16;
typedef __attribute__((ext_vector_type(4))) unsigned short u16x4;
typedef __attribute__((ext_vector_type(8))) unsigned short u16x8;
typedef __attribute__((ext_vector_type(4))) unsigned int u32x4;

__device__ __forceinline__ unsigned short f2b(float f) {
  __hip_bfloat16 h = __float2bfloat16(f);
  return __builtin_bit_cast(unsigned short, h);
}

__device__ __forceinline__ void gload_lds16(const void* g, void* l) {
  __builtin_amdgcn_global_load_lds(
      (const __attribute__((address_space(1))) unsigned int*)g,
      (__attribute__((address_space(3))) unsigned int*)l, 16, 0, 0);
}

__device__ __forceinline__ f32x16 mfma32(short8 a, short8 b, f32x16 c) {
  return __builtin_amdgcn_mfma_f32_32x32x16_bf16(a, b, c, 0, 0, 0);
}

__device__ __forceinline__ unsigned int cvtpk(float a, float b) {
  unsigned int r;
  asm("v_cvt_pk_bf16_f32 %0, %1, %2" : "=v"(r) : "v"(a), "v"(b));
  return r;
}

// ---------------- prepass: f32 -> bf16 linear convert (word+entity fused) ----
__global__ __launch_bounds__(256) void cvt_all(const float* __restrict__ sw,
                                               const float* __restrict__ se,
                                               unsigned short* __restrict__ dw,
                                               unsigned short* __restrict__ de) {
  int i = blockIdx.x * 256 + threadIdx.x;
  const float* s;
  unsigned short* d;
  int j;
  if (i < 524288) {
    s = sw; d = dw; j = i;
  } else {
    s = se; d = de; j = i - 524288;
    if (j >= 65536) return;
  }
  const f32x4* sp = (const f32x4*)s;
  f32x4 a = sp[2 * j];
  f32x4 b = sp[2 * j + 1];
  u16x8 o;
  o[0] = f2b(a[0]); o[1] = f2b(a[1]); o[2] = f2b(a[2]); o[3] = f2b(a[3]);
  o[4] = f2b(b[0]); o[5] = f2b(b[1]); o[6] = f2b(b[2]); o[7] = f2b(b[3]);
  ((u16x8*)d)[j] = o;
}

// ------------- prepass: weight transpose+convert: Wt[n][k] = bf16(W[k][n]) ----
struct WtransParams {
  const float* w[6];
  unsigned short* wt[6];
};

__global__ __launch_bounds__(256) void wtrans(WtransParams p) {
  __shared__ float t[32][33];
  const int z = blockIdx.z;
  const float* W = p.w[z];
  unsigned short* Wt = p.wt[z];
  const int bx = blockIdx.x;
  const int by = blockIdx.y;
  const int tx = threadIdx.x, ty = threadIdx.y;
#pragma unroll
  for (int i = 0; i < 4; ++i)
    t[ty + 8 * i][tx] = W[(by * 32 + ty + 8 * i) * 1024 + bx * 32 + tx];
  __syncthreads();
#pragma unroll
  for (int i = 0; i < 4; ++i)
    Wt[(bx * 32 + ty + 8 * i) * 1024 + by * 32 + tx] = f2b(t[tx][ty + 8 * i]);
}

// ---------------- merged batched projection GEMM ----------------
struct GemmJob {
  const unsigned short* Wt;  // [1024][1024] bf16, n-major
  const float* bias;
  unsigned short* out;
  int S;
  int s_off;
  int sshift;  // log2 rows-per-batch
  int trans;   // 0: out[bh][s][64]; 1: out[bh][64][2304] (V transposed)
  float scale;
};
struct Gemm2Params {
  const unsigned short* Aw;
  const unsigned short* Ae;
  GemmJob job[8];
};

__global__ __launch_bounds__(256) void gemm_qkv(Gemm2Params p) {
  __shared__ unsigned short As[128 * 64];
  __shared__ unsigned short Bs[128 * 64];
  const int tid = threadIdx.x;
  const int w = tid >> 6, lane = tid & 63;
  const int c = lane & 15, g = lane >> 4;
  const int z = blockIdx.z;
  const int y = blockIdx.y;
  const bool isw = y < 32;
  const GemmJob j = p.job[isw ? z : z + 4];
  const unsigned short* A = isw ? p.Aw : p.Ae;
  const long arow0 = (long)(isw ? y : y - 32) * 128;
  const unsigned short* B = j.Wt;
  const long brow0 = (long)blockIdx.x * 128;

  f32x4 acc[4][4] = {};

  for (int kt = 0; kt < 16; ++kt) {
    __syncthreads();
#pragma unroll
    for (int i = 0; i < 4; ++i) {
      int ch = i * 256 + tid;
      int row = ch >> 3;
      int k8 = ((ch & 7) ^ (row & 7)) << 3;
      const unsigned short* ga = A + (arow0 + row) * 1024 + kt * 64 + k8;
      const unsigned short* gb = B + (brow0 + row) * 1024 + kt * 64 + k8;
      gload_lds16(ga, As + (i * 256 + w * 64) * 8);
      gload_lds16(gb, Bs + (i * 256 + w * 64) * 8);
    }
    __syncthreads();
#pragma unroll
    for (int kf = 0; kf < 2; ++kf) {
      short8 av[4], bv[4];
#pragma unroll
      for (int mf = 0; mf < 4; ++mf) {
        int row = (w >> 1) * 64 + mf * 16 + c;
        int byte = (row * 128 + (kf * 32 + g * 8) * 2) ^ ((row & 7) << 4);
        av[mf] = *(const short8*)((const char*)As + byte);
      }
#pragma unroll
      for (int nf = 0; nf < 4; ++nf) {
        int row = (w & 1) * 64 + nf * 16 + c;
        int byte = (row * 128 + (kf * 32 + g * 8) * 2) ^ ((row & 7) << 4);
        bv[nf] = *(const short8*)((const char*)Bs + byte);
      }
      __builtin_amdgcn_s_setprio(1);
#pragma unroll
      for (int mf = 0; mf < 4; ++mf)
#pragma unroll
        for (int nf = 0; nf < 4; ++nf)
          acc[mf][nf] = __builtin_amdgcn_mfma_f32_16x16x32_bf16(av[mf], bv[nf],
                                                                acc[mf][nf], 0, 0, 0);
      __builtin_amdgcn_s_setprio(0);
    }
  }

  float biasv[4];
#pragma unroll
  for (int nf = 0; nf < 4; ++nf) {
    int n = (int)brow0 + (w & 1) * 64 + nf * 16 + c;
    biasv[nf] = j.bias[n];
  }
  const int smask = (1 << j.sshift) - 1;
  if (j.trans) {
#pragma unroll
    for (int mf = 0; mf < 4; ++mf) {
      int m0 = (int)arow0 + (w >> 1) * 64 + mf * 16 + g * 4;
      int b_ = m0 >> j.sshift;
      int s = (m0 & smask) + j.s_off;
#pragma unroll
      for (int nf = 0; nf < 4; ++nf) {
        int n = (int)brow0 + (w & 1) * 64 + nf * 16 + c;
        int hh = n >> 6, dd = n & 63;
        u16x4 pv;
#pragma unroll
        for (int r = 0; r < 4; ++r)
          pv[r] = f2b((acc[mf][nf][r] + biasv[nf]) * j.scale);
        *(u16x4*)(j.out + (((long)b_ * 16 + hh) * 64 + dd) * 2304 + s) = pv;
      }
    }
  } else {
#pragma unroll
    for (int mf = 0; mf < 4; ++mf) {
#pragma unroll
      for (int r = 0; r < 4; ++r) {
        int m = (int)arow0 + (w >> 1) * 64 + mf * 16 + g * 4 + r;
        int b_ = m >> j.sshift;
        int s = (m & smask) + j.s_off;
#pragma unroll
        for (int nf = 0; nf < 4; ++nf) {
          int n = (int)brow0 + (w & 1) * 64 + nf * 16 + c;
          int hh = n >> 6, dd = n & 63;
          float v = (acc[mf][nf][r] + biasv[nf]) * j.scale;
          j.out[(((long)b_ * 16 + hh) * j.S + s) * 64 + dd] = f2b(v);
        }
      }
    }
  }
}

// ---------------- flash attention (key-split x2, 64 q-rows per wave) ---------
// 1152 blocks (XCD-grouped) x 128 threads (2 waves). Each wave: 64 q-rows.
// 64-key tiles, K+V double-buffered in 32 KiB LDS. P = exp2(st) unnormalized;
// the common scale cancels in the merge divide. K/V ds_reads amortized 2x.
__global__ __launch_bounds__(128, 2) void attn_kernel(
    const unsigned short* __restrict__ qw2w, const unsigned short* __restrict__ qw2e,
    const unsigned short* __restrict__ qe2w, const unsigned short* __restrict__ qe2e,
    const unsigned short* __restrict__ Kg, const unsigned short* __restrict__ Vtg,
    float* __restrict__ po0, float* __restrict__ po1, float* __restrict__ lbuf) {
  __shared__ unsigned short smem[16384];  // 32 KiB: K dbuf [0,8KB)x2, V dbuf [16KB,32KB)

  const int tid = threadIdx.x;
  const int w = tid >> 6, lane = tid & 63;
  const int l31 = lane & 31, hf = lane >> 5;

  // XCD-grouped bijective remap: 1152 = 8 * 144; work = bh*36 + tile*2 + part
  const int flat = blockIdx.x;
  const int work = (flat & 7) * 144 + (flat >> 3);
  const int part = work & 1;
  const int tile = (work % 36) >> 1;
  const int hb = work / 36;
  const int head = hb & 15, b = hb >> 4;

  const bool isw = tile < 16;
  const int Sq = isw ? 2048 : 256;
  const int q0 = (isw ? tile : tile - 16) * 128 + w * 64;  // wave owns 64 q-rows
  const int bh = b * 16 + head;
  const unsigned short* Qa =
      (isw ? qw2w : qe2w) + ((long)bh * Sq + q0 + l31) * 64 + hf * 8;
  const unsigned short* Qb =
      (isw ? qw2e : qe2e) + ((long)bh * Sq + q0 + l31) * 64 + hf * 8;
  const unsigned short* Kb = Kg + (long)bh * 2304 * 64;
  const unsigned short* Vtb = Vtg + (long)bh * 64 * 2304;

  short8 qcur[2][4];  // [qh][kf]
#pragma unroll
  for (int qh = 0; qh < 2; ++qh)
#pragma unroll
    for (int kf = 0; kf < 4; ++kf)
      qcur[qh][kf] = *(const short8*)(Qa + qh * 32 * 64 + kf * 16);

  f32x16 o[2][2] = {};  // [qh][mf over d-halves]
  float lrun[2] = {0.f, 0.f};

  auto stage = [&](int t, int bufi) {
    const unsigned short* Kt = Kb + t * 4096;
    unsigned short* Klp = smem + bufi * 4096;
    unsigned short* Vlp = smem + 8192 + bufi * 4096;
#pragma unroll
    for (int i = 0; i < 4; ++i) {
      int ch = i * 128 + tid;
      int row = ch >> 3, c8 = ch & 7;
      int col = (c8 ^ (row & 7)) << 3;
      gload_lds16(Kt + row * 64 + col, Klp + (i * 128 + (tid & 64)) * 8);
      gload_lds16(Vtb + row * 2304 + t * 64 + col, Vlp + (i * 128 + (tid & 64)) * 8);
    }
  };

  const int t0 = part * 18, t1 = t0 + 18;
  stage(t0, 0);
  __syncthreads();
  int cur = 0;

  for (int t = t0; t < t1; ++t) {
    if (t == 32) {  // entity-key region: switch to the *2e query
#pragma unroll
      for (int qh = 0; qh < 2; ++qh)
#pragma unroll
        for (int kf = 0; kf < 4; ++kf)
          qcur[qh][kf] = *(const short8*)(Qb + qh * 32 * 64 + kf * 16);
    }
    if (t + 1 < t1) stage(t + 1, cur ^ 1);

    const char* Kbase = (const char*)(smem + cur * 4096);
    const char* Vbase = (const char*)(smem + 8192 + cur * 4096);

    // process 2 key-groups of 32 sequentially (keeps score liveness at 2xf32x16)
#pragma unroll
    for (int kg = 0; kg < 2; ++kg) {
      int row = kg * 32 + l31;
      int rb = (row * 128) | (hf * 16);
      int sw = (row & 7) << 4;
      short8 kfr[4];
#pragma unroll
      for (int kf = 0; kf < 4; ++kf)
        kfr[kf] = *(const short8*)(Kbase + ((rb + kf * 32) ^ sw));
      f32x16 st0 = {}, st1 = {};
      __builtin_amdgcn_s_setprio(1);
#pragma unroll
      for (int kf = 0; kf < 4; ++kf) {
        st0 = mfma32(kfr[kf], qcur[0][kf], st0);
        st1 = mfma32(kfr[kf], qcur[1][kf], st1);
      }
      __builtin_amdgcn_s_setprio(0);

      // softmax: P = exp2(st), no max subtraction (scale cancels in merge)
      float s0 = 0.f, s1 = 0.f, s2 = 0.f, s3 = 0.f;
      float u0 = 0.f, u1 = 0.f, u2 = 0.f, u3 = 0.f;
#pragma unroll
      for (int r = 0; r < 16; r += 4) {
        float p0 = __builtin_amdgcn_exp2f(st0[r + 0]);
        float p1 = __builtin_amdgcn_exp2f(st0[r + 1]);
        float p2 = __builtin_amdgcn_exp2f(st0[r + 2]);
        float p3 = __builtin_amdgcn_exp2f(st0[r + 3]);
        st0[r + 0] = p0; st0[r + 1] = p1; st0[r + 2] = p2; st0[r + 3] = p3;
        s0 += p0; s1 += p1; s2 += p2; s3 += p3;
        float q0_ = __builtin_amdgcn_exp2f(st1[r + 0]);
        float q1_ = __builtin_amdgcn_exp2f(st1[r + 1]);
        float q2_ = __builtin_amdgcn_exp2f(st1[r + 2]);
        float q3_ = __builtin_amdgcn_exp2f(st1[r + 3]);
        st1[r + 0] = q0_; st1[r + 1] = q1_; st1[r + 2] = q2_; st1[r + 3] = q3_;
        u0 += q0_; u1 += q1_; u2 += q2_; u3 += q3_;
      }
      lrun[0] += (s0 + s1) + (s2 + s3);
      lrun[1] += (u0 + u1) + (u2 + u3);

      // P -> bf16 B-frags in-register, PV accumulate (V frags shared across qh)
#pragma unroll
      for (int hs = 0; hs < 2; ++hs) {
        const int rbase = hs * 8;
        unsigned int a0 = cvtpk(st0[rbase + 0], st0[rbase + 1]);
        unsigned int a1 = cvtpk(st0[rbase + 2], st0[rbase + 3]);
        unsigned int b0 = cvtpk(st0[rbase + 4], st0[rbase + 5]);
        unsigned int b1 = cvtpk(st0[rbase + 6], st0[rbase + 7]);
        asm("v_permlane32_swap_b32 %0, %1" : "+v"(a0), "+v"(b0));
        asm("v_permlane32_swap_b32 %0, %1" : "+v"(a1), "+v"(b1));
        u32x4 pw0;
        pw0[0] = a0; pw0[1] = a1; pw0[2] = b0; pw0[3] = b1;
        short8 pf0 = __builtin_bit_cast(short8, pw0);
        unsigned int c0 = cvtpk(st1[rbase + 0], st1[rbase + 1]);
        unsigned int c1 = cvtpk(st1[rbase + 2], st1[rbase + 3]);
        unsigned int d0 = cvtpk(st1[rbase + 4], st1[rbase + 5]);
        unsigned int d1 = cvtpk(st1[rbase + 6], st1[rbase + 7]);
        asm("v_permlane32_swap_b32 %0, %1" : "+v"(c0), "+v"(d0));
        asm("v_permlane32_swap_b32 %0, %1" : "+v"(c1), "+v"(d1));
        u32x4 pw1;
        pw1[0] = c0; pw1[1] = c1; pw1[2] = d0; pw1[3] = d1;
        short8 pf1 = __builtin_bit_cast(short8, pw1);
        const int ks = kg * 2 + hs;
        short8 vf0, vf1;
        {
          int vrow = l31;
          int byte = ((vrow * 128) | (ks * 32 + hf * 16)) ^ ((vrow & 7) << 4);
          vf0 = *(const short8*)(Vbase + byte);
          vrow = 32 + l31;
          byte = ((vrow * 128) | (ks * 32 + hf * 16)) ^ ((vrow & 7) << 4);
          vf1 = *(const short8*)(Vbase + byte);
        }
        __builtin_amdgcn_s_setprio(1);
        o[0][0] = mfma32(vf0, pf0, o[0][0]);
        o[0][1] = mfma32(vf1, pf0, o[0][1]);
        o[1][0] = mfma32(vf0, pf1, o[1][0]);
        o[1][1] = mfma32(vf1, pf1, o[1][1]);
        __builtin_amdgcn_s_setprio(0);
      }
    }

    __syncthreads();
    cur ^= 1;
  }

  // epilogue: combine lane halves, write UNNORMALIZED partial o + l
  float lt0 = lrun[0] + __shfl_xor(lrun[0], 32);
  float lt1 = lrun[1] + __shfl_xor(lrun[1], 32);

  const int sgb = (isw ? 0 : 2048) + q0;
  if (hf == 0) {
    lbuf[(long)part * 73728 + bh * 2304 + sgb + l31] = lt0;
    lbuf[(long)part * 73728 + bh * 2304 + sgb + 32 + l31] = lt1;
  }

  float* po = part ? po1 : po0;
  float* ob = isw ? po + (((long)b * 2048 + q0) * 1024 + head * 64)
                  : po + (long)2 * 2048 * 1024 +
                        (((long)b * 256 + q0) * 1024 + head * 64);

  // per-wave private 4KB transpose buffer (LDS reused), 4 rounds (qh x d-half)
  float* E = (float*)smem + w * 1024;
#pragma unroll
  for (int qh = 0; qh < 2; ++qh) {
#pragma unroll
    for (int p = 0; p < 2; ++p) {
#pragma unroll
      for (int rg = 0; rg < 4; ++rg) {
        int off = rg * 8 + hf * 4;
        f32x4 v;
        v[0] = o[qh][p][rg * 4 + 0];
        v[1] = o[qh][p][rg * 4 + 1];
        v[2] = o[qh][p][rg * 4 + 2];
        v[3] = o[qh][p][rg * 4 + 3];
        *(f32x4*)(E + l31 * 32 + (off ^ ((l31 & 7) << 2))) = v;
      }
      asm volatile("s_waitcnt lgkmcnt(0)" ::: "memory");
      __builtin_amdgcn_sched_barrier(0);
#pragma unroll
      for (int i = 0; i < 4; ++i) {
        int qr = i * 8 + (lane >> 3);
        int cc = (lane & 7) * 4;
        f32x4 v = *(const f32x4*)(E + qr * 32 + (cc ^ ((qr & 7) << 2)));
        *(f32x4*)(ob + (long)(qh * 32 + qr) * 1024 + p * 32 + cc) = v;
      }
      asm volatile("s_waitcnt lgkmcnt(0)" ::: "memory");
      __builtin_amdgcn_sched_barrier(0);
    }
  }
}

// ---------------- merge: out = (o0 + o1) / (l0 + l1) ----------------
__global__ __launch_bounds__(256) void attn_merge(const float* __restrict__ po0,
                                                  const float* __restrict__ po1,
                                                  const float* __restrict__ lbuf,
                                                  float* __restrict__ out) {
  long i = ((long)blockIdx.x * 256 + threadIdx.x) * 4;
  if (i >= 4718592) return;
  int bh, sg;
  if (i < 4194304) {
    int b = (int)(i >> 21), s = (int)((i >> 10) & 2047), h = (int)((i >> 6) & 15);
    bh = b * 16 + h;
    sg = s;
  } else {
    long j = i - 4194304;
    int b = (int)(j >> 18), s = (int)((j >> 10) & 255), h = (int)((j >> 6) & 15);
    bh = b * 16 + h;
    sg = 2048 + s;
  }
  float l0 = lbuf[bh * 2304 + sg];
  float l1 = lbuf[73728 + bh * 2304 + sg];
  f32x4 a = *(const f32x4*)(po0 + i);
  f32x4 c = *(const f32x4*)(po1 + i);
  float inv = 1.f / (l0 + l1);
  f32x4 r = (a + c) * inv;
  *(f32x4*)(out + i) = r;
}

// ---------------- host ----------------
extern "C" void kernel_launch(void* const* d_in, const int* in_sizes, int n_in,
                              void* d_out, int out_size, void* d_ws, size_t ws_size,
                              hipStream_t stream) {
  (void)in_sizes; (void)n_in; (void)out_size; (void)ws_size;
  const float* word = (const float*)d_in[0];
  const float* ent = (const float*)d_in[1];

  char* ws = (char*)d_ws;
  size_t off = 0;
  auto alloc = [&](size_t bytes) {
    void* p = ws + off;
    off += (bytes + 255) & ~(size_t)255;
    return p;
  };
  // NOTE: po0 aliases [Xw, Xe, Wt) (22.0 MB front region) — those are dead by
  // the time attn_kernel writes po0 (all GEMMs complete first, same stream).
  unsigned short* Xw = (unsigned short*)alloc(4096ull * 1024 * 2);
  unsigned short* Xe = (unsigned short*)alloc(512ull * 1024 * 2);
  unsigned short* Wt[6];
  for (int i = 0; i < 6; ++i) Wt[i] = (unsigned short*)alloc(1024ull * 1024 * 2);
  unsigned short* qw2w = (unsigned short*)alloc(2ull * 16 * 2048 * 64 * 2);
  unsigned short* qw2e = (unsigned short*)alloc(2ull * 16 * 2048 * 64 * 2);
  unsigned short* qe2w = (unsigned short*)alloc(2ull * 16 * 256 * 64 * 2);
  unsigned short* qe2e = (unsigned short*)alloc(2ull * 16 * 256 * 64 * 2);
  unsigned short* Kbuf = (unsigned short*)alloc(2ull * 16 * 2304 * 64 * 2);
  unsigned short* Vtbuf = (unsigned short*)alloc(2ull * 16 * 64 * 2304 * 2);
  float* po1 = (float*)alloc(4718592ull * 4);
  float* lbuf = (float*)alloc(2ull * 73728 * 4);
  float* po0 = (float*)ws;  // aliases the dead prepass region

  cvt_all<<<2304, 256, 0, stream>>>(word, ent, Xw, Xe);

  WtransParams wp;
  wp.w[0] = (const float*)d_in[2];   // Wq
  wp.w[1] = (const float*)d_in[4];   // Wk
  wp.w[2] = (const float*)d_in[6];   // Wv
  wp.w[3] = (const float*)d_in[8];   // Ww2e
  wp.w[4] = (const float*)d_in[10];  // We2w
  wp.w[5] = (const float*)d_in[12];  // We2e
  for (int i = 0; i < 6; ++i) wp.wt[i] = Wt[i];
  wtrans<<<dim3(32, 32, 6), dim3(32, 8), 0, stream>>>(wp);

  const float* bq = (const float*)d_in[3];
  const float* bk = (const float*)d_in[5];
  const float* bv = (const float*)d_in[7];
  const float* bw2e = (const float*)d_in[9];
  const float* be2w = (const float*)d_in[11];
  const float* be2e = (const float*)d_in[13];
  const float qs = 0.125f * 1.44269504f;  // 1/sqrt(64) * log2(e): exp2-domain softmax

  Gemm2Params gp;
  gp.Aw = Xw;
  gp.Ae = Xe;
  gp.job[0] = {Wt[0], bq, qw2w, 2048, 0, 11, 0, qs};
  gp.job[1] = {Wt[3], bw2e, qw2e, 2048, 0, 11, 0, qs};
  gp.job[2] = {Wt[1], bk, Kbuf, 2304, 0, 11, 0, 1.f};
  gp.job[3] = {Wt[2], bv, Vtbuf, 2304, 0, 11, 1, 1.f};
  gp.job[4] = {Wt[4], be2w, qe2w, 256, 0, 8, 0, qs};
  gp.job[5] = {Wt[5], be2e, qe2e, 256, 0, 8, 0, qs};
  gp.job[6] = {Wt[1], bk, Kbuf, 2304, 2048, 8, 0, 1.f};
  gp.job[7] = {Wt[2], bv, Vtbuf, 2304, 2048, 8, 1, 1.f};
  gemm_qkv<<<dim3(8, 36, 4), 256, 0, stream>>>(gp);

  attn_kernel<<<1152, 128, 0, stream>>>(qw2w, qw2e, qe2w, qe2e, Kbuf, Vtbuf,
                                        po0, po1, lbuf);
  attn_merge<<<4608, 256, 0, stream>>>(po0, po1, lbuf, (float*)d_out);
}

// Round 9
// 149.053 us; speedup vs baseline: 1.3536x; 1.0392x over previous
//
#include <hip/hip_runtime.h>
#include <hip/hip_bf16.h>

typedef __attribute__((ext_vector_type(8))) short short8;
typedef __attribute__((ext_vector_type(4))) float f32x4;
typedef __attribute__((ext_vector_type(16))) float f32x16;
typedef __attribute__((ext_vector_type(4))) unsigned short u16x4;
typedef __attribute__((ext_vector_type(8))) unsigned short u16x8;
typedef __attribute__((ext_vector_type(4))) unsigned int u32x4;

__device__ __forceinline__ unsigned short f2b(float f) {
  __hip_bfloat16 h = __float2bfloat16(f);
  return __builtin_bit_cast(unsigned short, h);
}

__device__ __forceinline__ void gload_lds16(const void* g, void* l) {
  __builtin_amdgcn_global_load_lds(
      (const __attribute__((address_space(1))) unsigned int*)g,
      (__attribute__((address_space(3))) unsigned int*)l, 16, 0, 0);
}

__device__ __forceinline__ f32x16 mfma32(short8 a, short8 b, f32x16 c) {
  return __builtin_amdgcn_mfma_f32_32x32x16_bf16(a, b, c, 0, 0, 0);
}

__device__ __forceinline__ unsigned int cvtpk(float a, float b) {
  unsigned int r;
  asm("v_cvt_pk_bf16_f32 %0, %1, %2" : "=v"(r) : "v"(a), "v"(b));
  return r;
}

// ---------------- prepass: f32 -> bf16 linear convert (word+entity fused) ----
__global__ __launch_bounds__(256) void cvt_all(const float* __restrict__ sw,
                                               const float* __restrict__ se,
                                               unsigned short* __restrict__ dw,
                                               unsigned short* __restrict__ de) {
  int i = blockIdx.x * 256 + threadIdx.x;
  const float* s;
  unsigned short* d;
  int j;
  if (i < 524288) {
    s = sw; d = dw; j = i;
  } else {
    s = se; d = de; j = i - 524288;
    if (j >= 65536) return;
  }
  const f32x4* sp = (const f32x4*)s;
  f32x4 a = sp[2 * j];
  f32x4 b = sp[2 * j + 1];
  u16x8 o;
  o[0] = f2b(a[0]); o[1] = f2b(a[1]); o[2] = f2b(a[2]); o[3] = f2b(a[3]);
  o[4] = f2b(b[0]); o[5] = f2b(b[1]); o[6] = f2b(b[2]); o[7] = f2b(b[3]);
  ((u16x8*)d)[j] = o;
}

// ------------- prepass: weight transpose+convert: Wt[n][k] = bf16(W[k][n]) ----
struct WtransParams {
  const float* w[6];
  unsigned short* wt[6];
};

__global__ __launch_bounds__(256) void wtrans(WtransParams p) {
  __shared__ float t[32][33];
  const int z = blockIdx.z;
  const float* W = p.w[z];
  unsigned short* Wt = p.wt[z];
  const int bx = blockIdx.x;
  const int by = blockIdx.y;
  const int tx = threadIdx.x, ty = threadIdx.y;
#pragma unroll
  for (int i = 0; i < 4; ++i)
    t[ty + 8 * i][tx] = W[(by * 32 + ty + 8 * i) * 1024 + bx * 32 + tx];
  __syncthreads();
#pragma unroll
  for (int i = 0; i < 4; ++i)
    Wt[(bx * 32 + ty + 8 * i) * 1024 + by * 32 + tx] = f2b(t[tx][ty + 8 * i]);
}

// ---------------- merged batched projection GEMM ----------------
struct GemmJob {
  const unsigned short* Wt;  // [1024][1024] bf16, n-major
  const float* bias;
  unsigned short* out;
  int S;
  int s_off;
  int sshift;  // log2 rows-per-batch
  int trans;   // 0: out[bh][s][64]; 1: out[bh][64][2304] (V transposed)
  float scale;
};
struct Gemm2Params {
  const unsigned short* Aw;
  const unsigned short* Ae;
  GemmJob job[8];
};

__global__ __launch_bounds__(256) void gemm_qkv(Gemm2Params p) {
  __shared__ unsigned short As[128 * 64];
  __shared__ unsigned short Bs[128 * 64];
  const int tid = threadIdx.x;
  const int w = tid >> 6, lane = tid & 63;
  const int c = lane & 15, g = lane >> 4;
  const int z = blockIdx.z;
  const int y = blockIdx.y;
  const bool isw = y < 32;
  const GemmJob j = p.job[isw ? z : z + 4];
  const unsigned short* A = isw ? p.Aw : p.Ae;
  const long arow0 = (long)(isw ? y : y - 32) * 128;
  const unsigned short* B = j.Wt;
  const long brow0 = (long)blockIdx.x * 128;

  f32x4 acc[4][4] = {};

  for (int kt = 0; kt < 16; ++kt) {
    __syncthreads();
#pragma unroll
    for (int i = 0; i < 4; ++i) {
      int ch = i * 256 + tid;
      int row = ch >> 3;
      int k8 = ((ch & 7) ^ (row & 7)) << 3;
      const unsigned short* ga = A + (arow0 + row) * 1024 + kt * 64 + k8;
      const unsigned short* gb = B + (brow0 + row) * 1024 + kt * 64 + k8;
      gload_lds16(ga, As + (i * 256 + w * 64) * 8);
      gload_lds16(gb, Bs + (i * 256 + w * 64) * 8);
    }
    __syncthreads();
#pragma unroll
    for (int kf = 0; kf < 2; ++kf) {
      short8 av[4], bv[4];
#pragma unroll
      for (int mf = 0; mf < 4; ++mf) {
        int row = (w >> 1) * 64 + mf * 16 + c;
        int byte = (row * 128 + (kf * 32 + g * 8) * 2) ^ ((row & 7) << 4);
        av[mf] = *(const short8*)((const char*)As + byte);
      }
#pragma unroll
      for (int nf = 0; nf < 4; ++nf) {
        int row = (w & 1) * 64 + nf * 16 + c;
        int byte = (row * 128 + (kf * 32 + g * 8) * 2) ^ ((row & 7) << 4);
        bv[nf] = *(const short8*)((const char*)Bs + byte);
      }
      __builtin_amdgcn_s_setprio(1);
#pragma unroll
      for (int mf = 0; mf < 4; ++mf)
#pragma unroll
        for (int nf = 0; nf < 4; ++nf)
          acc[mf][nf] = __builtin_amdgcn_mfma_f32_16x16x32_bf16(av[mf], bv[nf],
                                                                acc[mf][nf], 0, 0, 0);
      __builtin_amdgcn_s_setprio(0);
    }
  }

  float biasv[4];
#pragma unroll
  for (int nf = 0; nf < 4; ++nf) {
    int n = (int)brow0 + (w & 1) * 64 + nf * 16 + c;
    biasv[nf] = j.bias[n];
  }
  const int smask = (1 << j.sshift) - 1;
  if (j.trans) {
#pragma unroll
    for (int mf = 0; mf < 4; ++mf) {
      int m0 = (int)arow0 + (w >> 1) * 64 + mf * 16 + g * 4;
      int b_ = m0 >> j.sshift;
      int s = (m0 & smask) + j.s_off;
#pragma unroll
      for (int nf = 0; nf < 4; ++nf) {
        int n = (int)brow0 + (w & 1) * 64 + nf * 16 + c;
        int hh = n >> 6, dd = n & 63;
        u16x4 pv;
#pragma unroll
        for (int r = 0; r < 4; ++r)
          pv[r] = f2b((acc[mf][nf][r] + biasv[nf]) * j.scale);
        *(u16x4*)(j.out + (((long)b_ * 16 + hh) * 64 + dd) * 2304 + s) = pv;
      }
    }
  } else {
#pragma unroll
    for (int mf = 0; mf < 4; ++mf) {
#pragma unroll
      for (int r = 0; r < 4; ++r) {
        int m = (int)arow0 + (w >> 1) * 64 + mf * 16 + g * 4 + r;
        int b_ = m >> j.sshift;
        int s = (m & smask) + j.s_off;
#pragma unroll
        for (int nf = 0; nf < 4; ++nf) {
          int n = (int)brow0 + (w & 1) * 64 + nf * 16 + c;
          int hh = n >> 6, dd = n & 63;
          float v = (acc[mf][nf][r] + biasv[nf]) * j.scale;
          j.out[(((long)b_ * 16 + hh) * j.S + s) * 64 + dd] = f2b(v);
        }
      }
    }
  }
}

// ------- flash attention: barrier-free wave-autonomous in-block key-split ----
// 1152 blocks (XCD-grouped) x 256 thr. Block = one 64-row q-tile; wave w owns
// keys [w*576,(w+1)*576) as 18 x 32-key tiles with a PRIVATE 16 KiB K/V dbuf.
// No barriers in main loop (per-wave counted vmcnt pipeline). P = exp2(st)
// unnormalized; per-wave (o,l) partials summed cross-wave at epilogue in LDS.
__global__ __launch_bounds__(256, 2) void attn_kernel(
    const unsigned short* __restrict__ qw2w, const unsigned short* __restrict__ qw2e,
    const unsigned short* __restrict__ qe2w, const unsigned short* __restrict__ qe2e,
    const unsigned short* __restrict__ Kg, const unsigned short* __restrict__ Vtg,
    float* __restrict__ out) {
  __shared__ unsigned short smem[33280];  // 65 KB: 4 x 16KB wave dbuf + 1KB Lbuf

  const int tid = threadIdx.x;
  const int w = tid >> 6, lane = tid & 63;
  const int l31 = lane & 31, hf = lane >> 5;

  // XCD-grouped bijective remap: 1152 = 8 * 144; work = bh*36 + tile
  const int flat = blockIdx.x;
  const int work = (flat & 7) * 144 + (flat >> 3);
  const int tile = work % 36;
  const int hb = work / 36;
  const int head = hb & 15, b = hb >> 4;

  const bool isw = tile < 32;
  const int Sq = isw ? 2048 : 256;
  const int q0 = (isw ? tile : tile - 32) * 64;
  const int bh = b * 16 + head;
  const unsigned short* Qa =
      (isw ? qw2w : qe2w) + ((long)bh * Sq + q0 + l31) * 64 + hf * 8;
  const unsigned short* Qb =
      (isw ? qw2e : qe2e) + ((long)bh * Sq + q0 + l31) * 64 + hf * 8;
  const unsigned short* Kb = Kg + (long)bh * 2304 * 64;
  const unsigned short* Vtb = Vtg + (long)bh * 64 * 2304;

  short8 qcur[2][4];  // [qh][kf]
#pragma unroll
  for (int qh = 0; qh < 2; ++qh)
#pragma unroll
    for (int kf = 0; kf < 4; ++kf)
      qcur[qh][kf] = *(const short8*)(Qa + qh * 2048 + kf * 16);

  f32x16 o[2][2] = {};  // [qh][mf over d-halves]
  float lrun[2] = {0.f, 0.f};

  // stage one 32-key tile into this wave's buffer bufi:
  // K [32 key-rows][128B swizzled], V packed rows: row r = {d=r | d=r+32} x 32 keys
  auto stage = [&](int t, int bufi) {
    unsigned short* kb = smem + w * 8192 + bufi * 4096;
    unsigned short* vb = kb + 2048;
    const int key0s = w * 576 + t * 32;
#pragma unroll
    for (int i = 0; i < 4; ++i) {
      int c = i * 64 + lane;
      int row = c >> 3, slot = c & 7;
      int sl = slot ^ (row & 7);  // pre-swizzled logical slot
      gload_lds16(Kb + (key0s + row) * 64 + sl * 8, kb + i * 512);
      int d = row + ((sl >> 2) << 5);
      int k8 = (sl & 3) << 3;
      gload_lds16(Vtb + (long)d * 2304 + key0s + k8, vb + i * 512);
    }
  };

  stage(0, 0);
  int cur = 0;
  const int swz = (l31 & 7) << 4;

  for (int t = 0; t < 18; ++t) {
    if (w * 576 + t * 32 == 2048) {  // entity-key region (wave 3, t=10)
#pragma unroll
      for (int qh = 0; qh < 2; ++qh)
#pragma unroll
        for (int kf = 0; kf < 4; ++kf)
          qcur[qh][kf] = *(const short8*)(Qb + qh * 2048 + kf * 16);
    }
    if (t < 17) {
      stage(t + 1, cur ^ 1);
      asm volatile("s_waitcnt vmcnt(8)" ::: "memory");  // stage(t) landed
    } else {
      asm volatile("s_waitcnt vmcnt(0)" ::: "memory");
    }
    __builtin_amdgcn_sched_barrier(0);

    const char* KbaseC = (const char*)(smem + w * 8192 + cur * 4096);
    const char* VbaseC = KbaseC + 4096;

    // QK^T: ST[key][q] for this wave's 32 keys x 64 q (2 qh)
    short8 kfr[4];
#pragma unroll
    for (int kf = 0; kf < 4; ++kf)
      kfr[kf] = *(const short8*)(KbaseC + l31 * 128 + (((kf * 32) | (hf * 16)) ^ swz));
    f32x16 st0 = {}, st1 = {};
    __builtin_amdgcn_s_setprio(1);
#pragma unroll
    for (int kf = 0; kf < 4; ++kf) {
      st0 = mfma32(kfr[kf], qcur[0][kf], st0);
      st1 = mfma32(kfr[kf], qcur[1][kf], st1);
    }
    __builtin_amdgcn_s_setprio(0);

    // softmax: P = exp2(st) (scale cancels at normalization)
    float s0 = 0.f, s1 = 0.f, s2 = 0.f, s3 = 0.f;
    float u0 = 0.f, u1 = 0.f, u2 = 0.f, u3 = 0.f;
#pragma unroll
    for (int r = 0; r < 16; r += 4) {
      float p0 = __builtin_amdgcn_exp2f(st0[r + 0]);
      float p1 = __builtin_amdgcn_exp2f(st0[r + 1]);
      float p2 = __builtin_amdgcn_exp2f(st0[r + 2]);
      float p3 = __builtin_amdgcn_exp2f(st0[r + 3]);
      st0[r + 0] = p0; st0[r + 1] = p1; st0[r + 2] = p2; st0[r + 3] = p3;
      s0 += p0; s1 += p1; s2 += p2; s3 += p3;
      float q0_ = __builtin_amdgcn_exp2f(st1[r + 0]);
      float q1_ = __builtin_amdgcn_exp2f(st1[r + 1]);
      float q2_ = __builtin_amdgcn_exp2f(st1[r + 2]);
      float q3_ = __builtin_amdgcn_exp2f(st1[r + 3]);
      st1[r + 0] = q0_; st1[r + 1] = q1_; st1[r + 2] = q2_; st1[r + 3] = q3_;
      u0 += q0_; u1 += q1_; u2 += q2_; u3 += q3_;
    }
    lrun[0] += (s0 + s1) + (s2 + s3);
    lrun[1] += (u0 + u1) + (u2 + u3);

    // P -> bf16 B-frags in-register, PV accumulate
#pragma unroll
    for (int hs = 0; hs < 2; ++hs) {
      const int rbase = hs * 8;
      unsigned int a0 = cvtpk(st0[rbase + 0], st0[rbase + 1]);
      unsigned int a1 = cvtpk(st0[rbase + 2], st0[rbase + 3]);
      unsigned int b0 = cvtpk(st0[rbase + 4], st0[rbase + 5]);
      unsigned int b1 = cvtpk(st0[rbase + 6], st0[rbase + 7]);
      asm("v_permlane32_swap_b32 %0, %1" : "+v"(a0), "+v"(b0));
      asm("v_permlane32_swap_b32 %0, %1" : "+v"(a1), "+v"(b1));
      u32x4 pw0;
      pw0[0] = a0; pw0[1] = a1; pw0[2] = b0; pw0[3] = b1;
      short8 pf0 = __builtin_bit_cast(short8, pw0);
      unsigned int c0 = cvtpk(st1[rbase + 0], st1[rbase + 1]);
      unsigned int c1 = cvtpk(st1[rbase + 2], st1[rbase + 3]);
      unsigned int d0 = cvtpk(st1[rbase + 4], st1[rbase + 5]);
      unsigned int d1 = cvtpk(st1[rbase + 6], st1[rbase + 7]);
      asm("v_permlane32_swap_b32 %0, %1" : "+v"(c0), "+v"(d0));
      asm("v_permlane32_swap_b32 %0, %1" : "+v"(c1), "+v"(d1));
      u32x4 pw1;
      pw1[0] = c0; pw1[1] = c1; pw1[2] = d0; pw1[3] = d1;
      short8 pf1 = __builtin_bit_cast(short8, pw1);
      short8 vf0 = *(const short8*)(VbaseC + l31 * 128 +
                                    (((hs * 2 + hf) ^ (l31 & 7)) << 4));
      short8 vf1 = *(const short8*)(VbaseC + l31 * 128 +
                                    (((4 + hs * 2 + hf) ^ (l31 & 7)) << 4));
      __builtin_amdgcn_s_setprio(1);
      o[0][0] = mfma32(vf0, pf0, o[0][0]);
      o[0][1] = mfma32(vf1, pf0, o[0][1]);
      o[1][0] = mfma32(vf0, pf1, o[1][0]);
      o[1][1] = mfma32(vf1, pf1, o[1][1]);
      __builtin_amdgcn_s_setprio(0);
    }

    cur ^= 1;
  }

  // ---- epilogue: cross-wave (o,l) reduction in LDS, normalize, store ----
  float lt0 = lrun[0] + __shfl_xor(lrun[0], 32);
  float lt1 = lrun[1] + __shfl_xor(lrun[1], 32);
  float* Lf = (float*)(smem + 32768);
  if (lane < 32) {
    Lf[w * 64 + lane] = lt0;
    Lf[w * 64 + 32 + lane] = lt1;
  }
  // unscaled o partials -> this wave's own 16KB region, swizzled [q][d4]
#pragma unroll
  for (int qh = 0; qh < 2; ++qh)
#pragma unroll
    for (int mf = 0; mf < 2; ++mf)
#pragma unroll
      for (int rg = 0; rg < 4; ++rg) {
        int q = qh * 32 + l31;
        int d4 = mf * 8 + rg * 2 + hf;
        f32x4 v;
        v[0] = o[qh][mf][rg * 4 + 0];
        v[1] = o[qh][mf][rg * 4 + 1];
        v[2] = o[qh][mf][rg * 4 + 2];
        v[3] = o[qh][mf][rg * 4 + 3];
        *(f32x4*)((char*)smem + w * 16384 + q * 256 + ((d4 ^ (q & 7)) << 4)) = v;
      }
  __syncthreads();

  float* ob = isw ? out + (((long)b * 2048 + q0) * 1024 + head * 64)
                  : out + 4194304 + (((long)b * 256 + q0) * 1024 + head * 64);
  const int q = tid >> 2;  // 0..63
  float inv = 1.f / (Lf[q] + Lf[64 + q] + Lf[128 + q] + Lf[192 + q]);
#pragma unroll
  for (int i = 0; i < 4; ++i) {
    int c = (tid & 3) * 4 + i;  // d4 chunk 0..15
    f32x4 s = {};
#pragma unroll
    for (int ww = 0; ww < 4; ++ww) {
      f32x4 pv = *(const f32x4*)((const char*)smem + ww * 16384 + q * 256 +
                                 ((c ^ (q & 7)) << 4));
      s += pv;
    }
    s *= inv;
    *(f32x4*)(ob + (long)q * 1024 + c * 4) = s;
  }
}

// ---------------- host ----------------
extern "C" void kernel_launch(void* const* d_in, const int* in_sizes, int n_in,
                              void* d_out, int out_size, void* d_ws, size_t ws_size,
                              hipStream_t stream) {
  (void)in_sizes; (void)n_in; (void)out_size; (void)ws_size;
  const float* word = (const float*)d_in[0];
  const float* ent = (const float*)d_in[1];

  char* ws = (char*)d_ws;
  size_t off = 0;
  auto alloc = [&](size_t bytes) {
    void* p = ws + off;
    off += (bytes + 255) & ~(size_t)255;
    return p;
  };
  unsigned short* Xw = (unsigned short*)alloc(4096ull * 1024 * 2);
  unsigned short* Xe = (unsigned short*)alloc(512ull * 1024 * 2);
  unsigned short* Wt[6];
  for (int i = 0; i < 6; ++i) Wt[i] = (unsigned short*)alloc(1024ull * 1024 * 2);
  unsigned short* qw2w = (unsigned short*)alloc(2ull * 16 * 2048 * 64 * 2);
  unsigned short* qw2e = (unsigned short*)alloc(2ull * 16 * 2048 * 64 * 2);
  unsigned short* qe2w = (unsigned short*)alloc(2ull * 16 * 256 * 64 * 2);
  unsigned short* qe2e = (unsigned short*)alloc(2ull * 16 * 256 * 64 * 2);
  unsigned short* Kbuf = (unsigned short*)alloc(2ull * 16 * 2304 * 64 * 2);
  unsigned short* Vtbuf = (unsigned short*)alloc(2ull * 16 * 64 * 2304 * 2);

  cvt_all<<<2304, 256, 0, stream>>>(word, ent, Xw, Xe);

  WtransParams wp;
  wp.w[0] = (const float*)d_in[2];   // Wq
  wp.w[1] = (const float*)d_in[4];   // Wk
  wp.w[2] = (const float*)d_in[6];   // Wv
  wp.w[3] = (const float*)d_in[8];   // Ww2e
  wp.w[4] = (const float*)d_in[10];  // We2w
  wp.w[5] = (const float*)d_in[12];  // We2e
  for (int i = 0; i < 6; ++i) wp.wt[i] = Wt[i];
  wtrans<<<dim3(32, 32, 6), dim3(32, 8), 0, stream>>>(wp);

  const float* bq = (const float*)d_in[3];
  const float* bk = (const float*)d_in[5];
  const float* bv = (const float*)d_in[7];
  const float* bw2e = (const float*)d_in[9];
  const float* be2w = (const float*)d_in[11];
  const float* be2e = (const float*)d_in[13];
  const float qs = 0.125f * 1.44269504f;  // 1/sqrt(64) * log2(e): exp2-domain softmax

  Gemm2Params gp;
  gp.Aw = Xw;
  gp.Ae = Xe;
  gp.job[0] = {Wt[0], bq, qw2w, 2048, 0, 11, 0, qs};
  gp.job[1] = {Wt[3], bw2e, qw2e, 2048, 0, 11, 0, qs};
  gp.job[2] = {Wt[1], bk, Kbuf, 2304, 0, 11, 0, 1.f};
  gp.job[3] = {Wt[2], bv, Vtbuf, 2304, 0, 11, 1, 1.f};
  gp.job[4] = {Wt[4], be2w, qe2w, 256, 0, 8, 0, qs};
  gp.job[5] = {Wt[5], be2e, qe2e, 256, 0, 8, 0, qs};
  gp.job[6] = {Wt[1], bk, Kbuf, 2304, 2048, 8, 0, 1.f};
  gp.job[7] = {Wt[2], bv, Vtbuf, 2304, 2048, 8, 1, 1.f};
  gemm_qkv<<<dim3(8, 36, 4), 256, 0, stream>>>(gp);

  attn_kernel<<<1152, 256, 0, stream>>>(qw2w, qw2e, qe2w, qe2e, Kbuf, Vtbuf,
                                        (float*)d_out);
}